// Round 1
// 390.514 us; speedup vs baseline: 1.2063x; 1.2063x over previous
//
#include <hip/hip_runtime.h>
#include <math.h>

// Problem constants
#define NSEQ 4
#define BATCH 256
#define T 64
#define FIN 32
#define S 512
#define KTOT 544     // FIN + S unified k-dimension

// Pipelined decomposition: 4 lanes concurrent (lane i lags i-1 by 1 step).
// Per lane: 16 groups x 16 rows, 4 slice-WGs x 128 cols. 4*16*4 = 256 WGs.
// NT=512 (8 waves, 1 WG/CU, 2 waves/SIMD). Wave -> one 16x16 col-tile,
// 17 K-tiles of mfma_f32_16x16x32_bf16, SPLIT-BF16 (hi+lo residual, 3
// products) for fp32-grade accuracy.
// vs previous 8-slice version: halves the per-step all-to-all coherent
// traffic (full-row h/p re-reads amplified 4x instead of 8x) and halves
// the sync fan-in (4 counter bumps/step per group instead of 8).
#define NT 512
#define NWG 256
#define RPG 16
#define SW 128       // cols per slice-WG
#define NSL 4        // slices per group
#define DEPTH 4
#define NKT 17       // K-tiles of 32 (544/32)

// ws float offsets
#define RING_SZ  (4ull * DEPTH * BATCH * S)        // 8 MB state ring
#define OUTP_OFF RING_SZ                            // [gid][sl][16] partials
#define CTL_OFF  (RING_SZ + 16384ull)               // counters: gid*32 uints

#define FLAG_MAGIC 0x13572468u

#define AS 552   // A-LDS row stride in bf16 elems (544 + 8 pad)

typedef __attribute__((ext_vector_type(8))) short short8;  // 8 bf16 (4 VGPRs)
typedef __attribute__((ext_vector_type(4))) float f32x4;   // MFMA C/D

// ---- split-bf16: value = hi (truncated bf16) + lo (bf16 of residual) ------
__device__ __forceinline__ unsigned short bf_hi(float f) {
  return (unsigned short)(__float_as_uint(f) >> 16);
}
__device__ __forceinline__ float bf_hi_f(float f) {
  return __uint_as_float(__float_as_uint(f) & 0xFFFF0000u);
}

__device__ __forceinline__ unsigned ld_cnt(const unsigned* p) {
  return __hip_atomic_load(p, __ATOMIC_RELAXED, __HIP_MEMORY_SCOPE_AGENT);
}

// ---- coherent (MALL) ring I/O via sc0 sc1 asm (R4-proven) -----------------
__device__ __forceinline__ void cstore1(float* p, float v) {
  asm volatile("global_store_dword %0, %1, off sc0 sc1" :: "v"(p), "v"(v) : "memory");
}
__device__ __forceinline__ float cload1(const float* p) {
  float v;
  asm volatile("global_load_dword %0, %1, off sc0 sc1\n\ts_waitcnt vmcnt(0)"
               : "=v"(v) : "v"(p) : "memory");
  return v;
}
__device__ __forceinline__ void cload_row(float4* d, const float* p) {
  asm volatile(
      "global_load_dwordx4 %0, %4, off sc0 sc1\n\t"
      "global_load_dwordx4 %1, %4, off offset:512 sc0 sc1\n\t"
      "global_load_dwordx4 %2, %4, off offset:1024 sc0 sc1\n\t"
      "global_load_dwordx4 %3, %4, off offset:1536 sc0 sc1\n\t"
      "s_waitcnt vmcnt(0)"
      : "=&v"(d[0]), "=&v"(d[1]), "=&v"(d[2]), "=&v"(d[3])
      : "v"(p) : "memory");
}
__device__ __forceinline__ void cload_row2(float4* h, float4* q,
                                           const float* ph, const float* pp) {
  asm volatile(
      "global_load_dwordx4 %0, %8, off sc0 sc1\n\t"
      "global_load_dwordx4 %1, %8, off offset:512 sc0 sc1\n\t"
      "global_load_dwordx4 %2, %8, off offset:1024 sc0 sc1\n\t"
      "global_load_dwordx4 %3, %8, off offset:1536 sc0 sc1\n\t"
      "global_load_dwordx4 %4, %9, off sc0 sc1\n\t"
      "global_load_dwordx4 %5, %9, off offset:512 sc0 sc1\n\t"
      "global_load_dwordx4 %6, %9, off offset:1024 sc0 sc1\n\t"
      "global_load_dwordx4 %7, %9, off offset:1536 sc0 sc1\n\t"
      "s_waitcnt vmcnt(0)"
      : "=&v"(h[0]), "=&v"(h[1]), "=&v"(h[2]), "=&v"(h[3]),
        "=&v"(q[0]), "=&v"(q[1]), "=&v"(q[2]), "=&v"(q[3])
      : "v"(ph), "v"(pp) : "memory");
}

extern "C" __global__ void __launch_bounds__(NT, 1)
rnn_mfma(const float* __restrict__ x,      // [4][256][64][32]
         const float* __restrict__ Wcell,  // [4][544][512]
         const float* __restrict__ bcell,  // [4][512]
         const float* __restrict__ Wcomb,  // [3][1024]
         const float* __restrict__ bcomb,  // [3]
         const float* __restrict__ Wout,   // [512]
         float* __restrict__ out,          // [1024] = [lane][batch]
         float* __restrict__ ws)
{
  const int b    = blockIdx.x;
  const int sl   = b & 3;          // slice (0..3)
  const int gid  = b >> 2;         // 0..63 = lane*16 + grp
  const int lane = gid >> 4;       // RNN lane
  const int grp  = gid & 15;
  const int r0 = grp * RPG, sb = sl * SW;
  const int tid = threadIdx.x;

  __shared__ __align__(16) unsigned short A1[RPG * AS];  // 17.3 KB hi [x|hc]
  __shared__ __align__(16) unsigned short A2[RPG * AS];  // 17.3 KB lo
  __shared__ float wg_lds[2 * S];                        //  4.0 KB gate weights
  __shared__ float obuf[128];
  __shared__ float fbuf[64];

  float* ring = ws;
  unsigned* ctl      = (unsigned*)(ws + CTL_OFF);
  unsigned* cnt_own  = ctl + gid * 32;
  unsigned* flg_own  = cnt_own + 16;
  unsigned* cnt_prod = ctl + (gid - 16) * 32;  // valid iff lane>0
  unsigned* cnt_cons = ctl + (gid + 16) * 32;  // valid iff lane<3

  // ---- init handshake (poison-keyed flag) ----
  if (sl == 0 && tid == 0) {
    __hip_atomic_store(cnt_own, 0u, __ATOMIC_RELAXED, __HIP_MEMORY_SCOPE_AGENT);
    __hip_atomic_store(flg_own, FLAG_MAGIC, __ATOMIC_RELEASE, __HIP_MEMORY_SCOPE_AGENT);
  }
  if (tid == 0) {
    while (__hip_atomic_load(flg_own, __ATOMIC_ACQUIRE, __HIP_MEMORY_SCOPE_AGENT) != FLAG_MAGIC)
      __builtin_amdgcn_s_sleep(1);
    if (lane > 0)
      while (__hip_atomic_load(cnt_prod + 16, __ATOMIC_ACQUIRE, __HIP_MEMORY_SCOPE_AGENT) != FLAG_MAGIC)
        __builtin_amdgcn_s_sleep(1);
    if (lane < 3)
      while (__hip_atomic_load(cnt_cons + 16, __ATOMIC_ACQUIRE, __HIP_MEMORY_SCOPE_AGENT) != FLAG_MAGIC)
        __builtin_amdgcn_s_sleep(1);
  }

  // ---- per-thread constants ----
  const float* Wc = Wcell + (size_t)lane * KTOT * S;
  // MFMA mapping: wave wt (0..7) owns cols [sb+wt*16, +16); within wave:
  //   A-frag: row m = wl&15, k = q*8+j   (q = wl>>4)
  //   B-frag: col n = wl&15, k = q*8+j
  //   C/D:    col  = wl&15, row = q*4+reg
  const int wl = tid & 63, wt = tid >> 6;
  const int bn = wl & 15, q = wl >> 4;
  const int ncol = sb + wt * 16 + bn;
  short8 B1[NKT], B2[NKT];   // split-bf16 weight frags: 136 regs, static
  #pragma unroll
  for (int kt = 0; kt < NKT; ++kt) {
    short8 b1, b2;
    #pragma unroll
    for (int j = 0; j < 8; ++j) {
      const float w = Wc[(size_t)(kt * 32 + q * 8 + j) * S + ncol];
      b1[j] = (short)bf_hi(w);
      b2[j] = (short)bf_hi(w - bf_hi_f(w));
    }
    B1[kt] = b1; B2[kt] = b2;
  }
  const float bcv = bcell[lane * S + ncol];
  const float wov = Wout[ncol];
  for (int idx = tid; idx < 2 * S; idx += NT)
    wg_lds[idx] = (lane > 0) ? Wcomb[(size_t)(lane - 1) * 2 * S + idx] : 0.0f;
  const float bg = (lane > 0) ? bcomb[lane - 1] : 0.0f;
  // stage/gate mapping: 32 threads per row, 16 rows in one pass
  const int grow = tid >> 5, gch = tid & 31;
  __syncthreads();

  float oacc[4] = {0.f, 0.f, 0.f, 0.f};

  for (int t = 0; t < T; ++t) {
    // ---- phase A: x stage (split-bf16 into A rows k<32) + polls ----
    {
      const float f0 = x[(((size_t)lane * BATCH + r0 + grow) * T + t) * FIN + gch];
      A1[grow * AS + gch] = bf_hi(f0);
      A2[grow * AS + gch] = bf_hi(f0 - bf_hi_f(f0));
    }
    if (tid == 0) {
      if (t > 0)                  while (ld_cnt(cnt_own)  < 4u * (unsigned)t) {}
      if (lane > 0)               while (ld_cnt(cnt_prod) < 4u * (unsigned)(t + 1)) {}
      if (lane < 3 && t >= DEPTH) while (ld_cnt(cnt_cons) < 4u * (unsigned)(t - 3)) {}
    }
    __syncthreads();

    // ---- phase B: ring loads + wave-local gate (fp32) + split-stage hc ----
    {
      const int row = grow;
      float4 hv[4], pv[4];
      const float* hb = ring + ((size_t)(lane * DEPTH + ((t - 1) & 3)) * BATCH + r0 + row) * S + gch * 4;
      const float* pb = ring + ((size_t)((lane - 1) * DEPTH + (t & 3)) * BATCH + r0 + row) * S + gch * 4;
      if (t > 0) {
        if (lane > 0) cload_row2(hv, pv, hb, pb);
        else          cload_row(hv, hb);
      } else {
        #pragma unroll
        for (int j = 0; j < 4; ++j) hv[j] = make_float4(0.f, 0.f, 0.f, 0.f);
        if (lane > 0) cload_row(pv, pb);
      }
      if (lane > 0) {
        float gs = 0.0f;
        #pragma unroll
        for (int j = 0; j < 4; ++j) {
          const float* wh = &wg_lds[j * 128 + gch * 4];
          const float* wp = wh + S;
          gs += hv[j].x * wh[0] + hv[j].y * wh[1] + hv[j].z * wh[2] + hv[j].w * wh[3];
          gs += pv[j].x * wp[0] + pv[j].y * wp[1] + pv[j].z * wp[2] + pv[j].w * wp[3];
        }
        gs += __shfl_xor(gs, 1);  gs += __shfl_xor(gs, 2);  gs += __shfl_xor(gs, 4);
        gs += __shfl_xor(gs, 8);  gs += __shfl_xor(gs, 16);  // 32-lane row halves
        const float w = 1.0f / (1.0f + __expf(-(gs + bg)));
        #pragma unroll
        for (int j = 0; j < 4; ++j) {  // hc = p + w*(h-p)
          hv[j].x = fmaf(w, hv[j].x - pv[j].x, pv[j].x);
          hv[j].y = fmaf(w, hv[j].y - pv[j].y, pv[j].y);
          hv[j].z = fmaf(w, hv[j].z - pv[j].z, pv[j].z);
          hv[j].w = fmaf(w, hv[j].w - pv[j].w, pv[j].w);
        }
      }
      #pragma unroll
      for (int j = 0; j < 4; ++j) {
        ushort4 h4, l4;
        h4.x = bf_hi(hv[j].x); l4.x = bf_hi(hv[j].x - bf_hi_f(hv[j].x));
        h4.y = bf_hi(hv[j].y); l4.y = bf_hi(hv[j].y - bf_hi_f(hv[j].y));
        h4.z = bf_hi(hv[j].z); l4.z = bf_hi(hv[j].z - bf_hi_f(hv[j].z));
        h4.w = bf_hi(hv[j].w); l4.w = bf_hi(hv[j].w - bf_hi_f(hv[j].w));
        const int ai = row * AS + 32 + j * 128 + gch * 4;
        *(ushort4*)&A1[ai] = h4;
        *(ushort4*)&A2[ai] = l4;
      }
    }
    __syncthreads();

    // ---- phase C: MFMA 16x16 tile, 17 K-tiles x 3 split products ----------
    f32x4 acc = {0.f, 0.f, 0.f, 0.f};
    {
      const unsigned short* ar1 = &A1[bn * AS + q * 8];
      const unsigned short* ar2 = &A2[bn * AS + q * 8];
      #pragma unroll
      for (int kt = 0; kt < NKT; ++kt) {
        const short8 a1 = *(const short8*)(ar1 + kt * 32);
        const short8 a2 = *(const short8*)(ar2 + kt * 32);
        acc = __builtin_amdgcn_mfma_f32_16x16x32_bf16(a1, B1[kt], acc, 0, 0, 0);
        acc = __builtin_amdgcn_mfma_f32_16x16x32_bf16(a1, B2[kt], acc, 0, 0, 0);
        acc = __builtin_amdgcn_mfma_f32_16x16x32_bf16(a2, B1[kt], acc, 0, 0, 0);
      }
    }

    // ---- epilogue: +bias, tanh, coherent ring store (D-layout direct) -----
    float* slot = ring + ((size_t)(lane * DEPTH + (t & 3)) * BATCH + r0) * S + sb;
    #pragma unroll
    for (int reg = 0; reg < 4; ++reg) {
      const float s2 = acc[reg] + bcv;
      const float aa = fabsf(s2), ee = __expf(2.0f * aa);
      const float tv = copysignf(1.0f - 2.0f / (ee + 1.0f), s2);
      cstore1(slot + (size_t)(q * 4 + reg) * S + wt * 16 + bn, tv);
      if (t == T - 1) oacc[reg] = tv * wov;
    }
    asm volatile("s_waitcnt vmcnt(0)" ::: "memory");  // own cstores at MALL
    __syncthreads();  // all threads drained -> safe to arrive + reuse A-LDS
    if (tid == 0)
      __hip_atomic_fetch_add(cnt_own, 1u, __ATOMIC_RELAXED, __HIP_MEMORY_SCOPE_AGENT);
  }

  // ---- output: out[lane*256 + r] = h_T[r] . Wout --------------------------
  #pragma unroll
  for (int reg = 0; reg < 4; ++reg) {
    float v = oacc[reg];
    v += __shfl_xor(v, 1); v += __shfl_xor(v, 2);
    v += __shfl_xor(v, 4); v += __shfl_xor(v, 8);  // sum 16 cols of the tile
    if (bn == 0) obuf[wt * 16 + q * 4 + reg] = v;
  }
  __syncthreads();
  if (tid < 16) {
    float v = 0.0f;
    #pragma unroll
    for (int w = 0; w < 8; ++w) v += obuf[w * 16 + tid];
    cstore1(ws + OUTP_OFF + (size_t)((gid * 4 + sl) * 16 + tid), v);
  }
  asm volatile("s_waitcnt vmcnt(0)" ::: "memory");
  __syncthreads();
  if (tid == 0)
    __hip_atomic_fetch_add(cnt_own, 1u, __ATOMIC_RELAXED, __HIP_MEMORY_SCOPE_AGENT);
  if (sl == 0) {
    if (tid == 0)
      while (ld_cnt(cnt_own) < 4u * (unsigned)(T + 1)) {}
    __syncthreads();
    if (tid < 64) {
      const int sli = tid >> 4, r = tid & 15;
      fbuf[tid] = cload1(ws + OUTP_OFF + (size_t)((gid * 4 + sli) * 16 + r));
    }
    __syncthreads();
    if (tid < 16) {
      float s2 = 0.f;
      #pragma unroll
      for (int sli = 0; sli < 4; ++sli) s2 += fbuf[sli * 16 + tid];
      out[lane * BATCH + r0 + tid] = s2;
    }
  }
}

extern "C" void kernel_launch(void* const* d_in, const int* in_sizes, int n_in,
                              void* d_out, int out_size, void* d_ws, size_t ws_size,
                              hipStream_t stream) {
  (void)in_sizes; (void)n_in; (void)out_size; (void)ws_size;
  rnn_mfma<<<dim3(NWG), dim3(NT), 0, stream>>>(
      (const float*)d_in[0],   // inputs
      (const float*)d_in[1],   // W_cell
      (const float*)d_in[2],   // b_cell
      (const float*)d_in[3],   // W_comb
      (const float*)d_in[4],   // b_comb
      (const float*)d_in[5],   // W_out
      (float*)d_out,
      (float*)d_ws);
}

// Round 5
// 367.922 us; speedup vs baseline: 1.2803x; 1.0614x over previous
//
#include <hip/hip_runtime.h>
#include <math.h>

// Problem constants
#define NSEQ 4
#define BATCH 256
#define T 64
#define FIN 32
#define S 512
#define KTOT 544     // FIN + S unified k-dimension

// Pipelined decomposition: 4 lanes concurrent (lane i lags i-1 by 1 step).
// Per lane: 16 groups x 16 rows, 4 slice-WGs x 128 cols. 4*16*4 = 256 WGs.
// NT=512 (8 waves). Wave -> one 16x16 col-tile, 17 K-tiles of
// mfma_f32_16x16x32_bf16, SPLIT-BF16 (hi+lo residual, 3 products).
//
// R5: retreat from XCD-local (sc0-only) mode entirely -- dirty sc0 lines in
// a single XCD's L2 leak across graph-replay iterations (re-poison doesn't
// invalidate them; later eviction clobbers freshly-zeroed MALL stamps).
// ALL inter-WG state uses the R1-proven sc0 sc1 (MALL) path. Kept levers:
//  * per-slice stamp words (plain sc0 sc1 stores) instead of contended
//    fetch_add counters -- no RMW line ping-pong.
//  * FUSED triple poll: one asm block, 3 dwordx4 stamp loads, ONE vmcnt(0)
//    -- 1 MALL round-trip per poll round instead of 3.
//  * all-wave polling + disjoint per-wave LDS rows in phases A/B -> the
//    phase-A barrier is gone; 2 barriers/step.
//  * poison-keyed FLAG_MAGIC init (ws is re-poisoned before every launch).
#define NT 512
#define NWG 256
#define RPG 16
#define SW 128       // cols per slice-WG
#define DEPTH 4
#define NKT 17       // K-tiles of 32 (544/32)

// ws float offsets (content is POISON at launch - never read before init)
#define RING_SZ  (4ull * DEPTH * BATCH * S)        // 8 MB state ring
#define OUTP_OFF RING_SZ                            // [gid][sl][16] partials
#define CTL_OFF  (RING_SZ + 16384ull)               // ctl area

#define FLAG_MAGIC 0x13572468u

#define AS 552   // A-LDS row stride in bf16 elems (544 + 8 pad)

typedef __attribute__((ext_vector_type(8))) short short8;      // 8 bf16
typedef __attribute__((ext_vector_type(4))) float f32x4;       // MFMA C/D
typedef __attribute__((ext_vector_type(4))) unsigned u32x4;    // asm 4-dword

// ---- split-bf16: value = hi (truncated bf16) + lo (bf16 of residual) ------
__device__ __forceinline__ unsigned short bf_hi(float f) {
  return (unsigned short)(__float_as_uint(f) >> 16);
}
__device__ __forceinline__ float bf_hi_f(float f) {
  return __uint_as_float(__float_as_uint(f) & 0xFFFF0000u);
}
__device__ __forceinline__ unsigned umin4(u32x4 v) {
  unsigned a = v[0] < v[1] ? v[0] : v[1];
  unsigned b = v[2] < v[3] ? v[2] : v[3];
  return a < b ? a : b;
}

// ---- MALL (system scope) coherent I/O: sc0 sc1 everywhere (R1-proven) -----
__device__ __forceinline__ void cstoreu_glb(unsigned* p, unsigned v) {
  asm volatile("global_store_dword %0, %1, off sc0 sc1" :: "v"(p), "v"(v) : "memory");
}
__device__ __forceinline__ void cstore4_glb(unsigned* p, u32x4 v) {
  asm volatile("global_store_dwordx4 %0, %1, off sc0 sc1" :: "v"(p), "v"(v) : "memory");
}
__device__ __forceinline__ unsigned cldu_glb(const unsigned* p) {
  unsigned v;
  asm volatile("global_load_dword %0, %1, off sc0 sc1\n\ts_waitcnt vmcnt(0)"
               : "=v"(v) : "v"(p) : "memory");
  return v;
}
__device__ __forceinline__ u32x4 cld4_glb(const unsigned* p) {
  u32x4 v;
  asm volatile("global_load_dwordx4 %0, %1, off sc0 sc1\n\ts_waitcnt vmcnt(0)"
               : "=v"(v) : "v"(p) : "memory");
  return v;
}
// fused triple stamp-line load: ONE vmcnt(0) for all three
__device__ __forceinline__ void cld3x4_glb(u32x4* a, u32x4* b, u32x4* c,
                                           const unsigned* pa, const unsigned* pb,
                                           const unsigned* pc) {
  asm volatile(
      "global_load_dwordx4 %0, %3, off sc0 sc1\n\t"
      "global_load_dwordx4 %1, %4, off sc0 sc1\n\t"
      "global_load_dwordx4 %2, %5, off sc0 sc1\n\t"
      "s_waitcnt vmcnt(0)"
      : "=&v"(*a), "=&v"(*b), "=&v"(*c)
      : "v"(pa), "v"(pb), "v"(pc) : "memory");
}
__device__ __forceinline__ void cstore1(float* p, float v) {
  asm volatile("global_store_dword %0, %1, off sc0 sc1" :: "v"(p), "v"(v) : "memory");
}
__device__ __forceinline__ float cload1(const float* p) {
  float v;
  asm volatile("global_load_dword %0, %1, off sc0 sc1\n\ts_waitcnt vmcnt(0)"
               : "=v"(v) : "v"(p) : "memory");
  return v;
}
__device__ __forceinline__ void cload_row(float4* d, const float* p) {
  asm volatile(
      "global_load_dwordx4 %0, %4, off sc0 sc1\n\t"
      "global_load_dwordx4 %1, %4, off offset:512 sc0 sc1\n\t"
      "global_load_dwordx4 %2, %4, off offset:1024 sc0 sc1\n\t"
      "global_load_dwordx4 %3, %4, off offset:1536 sc0 sc1\n\t"
      "s_waitcnt vmcnt(0)"
      : "=&v"(d[0]), "=&v"(d[1]), "=&v"(d[2]), "=&v"(d[3])
      : "v"(p) : "memory");
}
__device__ __forceinline__ void cload_row2(float4* h, float4* q,
                                           const float* ph, const float* pp) {
  asm volatile(
      "global_load_dwordx4 %0, %8, off sc0 sc1\n\t"
      "global_load_dwordx4 %1, %8, off offset:512 sc0 sc1\n\t"
      "global_load_dwordx4 %2, %8, off offset:1024 sc0 sc1\n\t"
      "global_load_dwordx4 %3, %8, off offset:1536 sc0 sc1\n\t"
      "global_load_dwordx4 %4, %9, off sc0 sc1\n\t"
      "global_load_dwordx4 %5, %9, off offset:512 sc0 sc1\n\t"
      "global_load_dwordx4 %6, %9, off offset:1024 sc0 sc1\n\t"
      "global_load_dwordx4 %7, %9, off offset:1536 sc0 sc1\n\t"
      "s_waitcnt vmcnt(0)"
      : "=&v"(h[0]), "=&v"(h[1]), "=&v"(h[2]), "=&v"(h[3]),
        "=&v"(q[0]), "=&v"(q[1]), "=&v"(q[2]), "=&v"(q[3])
      : "v"(ph), "v"(pp) : "memory");
}

// ctl layout (dwords, stride 64 per gid so stamps and flag sit on
// DIFFERENT 128B lines):
//   ctl + gid*64 + [0..3]  : per-slice stamps (one 128B line)
//   ctl + gid*64 + 32      : init flag (next 128B line)

extern "C" __global__ void __launch_bounds__(NT, 1)
rnn_mfma(const float* __restrict__ x,      // [4][256][64][32]
         const float* __restrict__ Wcell,  // [4][544][512]
         const float* __restrict__ bcell,  // [4][512]
         const float* __restrict__ Wcomb,  // [3][1024]
         const float* __restrict__ bcomb,  // [3]
         const float* __restrict__ Wout,   // [512]
         float* __restrict__ out,          // [1024] = [lane][batch]
         float* __restrict__ ws)
{
  // XCD-grouped block mapping (perf heuristic only; correctness is
  // placement-independent since everything goes through MALL):
  // b&7 spreads groups across XCDs; the 16 WGs of one comm set stay close.
  const int b    = blockIdx.x;
  const int o    = b >> 3;
  const int grp  = (b & 7) + 8 * (o >> 4);
  const int sub  = o & 15;
  const int lane = sub >> 2;
  const int sl   = sub & 3;
  const int gid  = lane * 16 + grp;
  const int r0 = grp * RPG, sb = sl * SW;
  const int tid = threadIdx.x;

  __shared__ __align__(16) unsigned short A1[RPG * AS];  // 17.3 KB hi [x|hc]
  __shared__ __align__(16) unsigned short A2[RPG * AS];  // 17.3 KB lo
  __shared__ float wg_lds[2 * S];                        //  4.0 KB gate weights
  __shared__ float obuf[128];
  __shared__ float fbuf[64];

  float* ring = ws;
  unsigned* ctl     = (unsigned*)(ws + CTL_OFF);
  unsigned* st_own  = ctl + gid * 64;          // 4 stamp dwords, 16B aligned
  unsigned* st_prod = ctl + (gid - 16) * 64;   // valid iff lane>0
  unsigned* st_cons = ctl + (gid + 16) * 64;   // valid iff lane<3
  unsigned* st_mine = st_own + sl;
  const unsigned* pp_poll = (lane > 0) ? st_prod : st_own;
  const unsigned* pc_poll = (lane < 3) ? st_cons : st_own;

  // ---- poison-keyed init (R1-proven): zero stamps, release flag ----
  if (sl == 0 && tid == 0) {
    const u32x4 z = {0u, 0u, 0u, 0u};
    cstore4_glb(st_own, z);
    asm volatile("s_waitcnt vmcnt(0)" ::: "memory");
    cstoreu_glb(st_own + 32, FLAG_MAGIC);
  }
  if (tid == 0) {
    // wait for all 4 zeroers of this comm set (lanes 0..3, same grp)
    #pragma unroll
    for (int l = 0; l < 4; ++l) {
      const unsigned* f = ctl + (l * 16 + grp) * 64 + 32;
      while (cldu_glb(f) != FLAG_MAGIC) __builtin_amdgcn_s_sleep(1);
    }
  }

  // ---- per-thread constants ----
  const float* Wc = Wcell + (size_t)lane * KTOT * S;
  // MFMA mapping: wave wt (0..7) owns cols [sb+wt*16, +16); within wave:
  //   A-frag: row m = wl&15, k = q*8+j   (q = wl>>4)
  //   B-frag: col n = wl&15, k = q*8+j
  //   C/D:    col  = wl&15, row = q*4+reg
  const int wl = tid & 63, wt = tid >> 6;
  const int bn = wl & 15, q = wl >> 4;
  const int ncol = sb + wt * 16 + bn;
  short8 B1[NKT], B2[NKT];   // split-bf16 weight frags: 136 regs, static
  #pragma unroll
  for (int kt = 0; kt < NKT; ++kt) {
    short8 b1, b2;
    #pragma unroll
    for (int j = 0; j < 8; ++j) {
      const float w = Wc[(size_t)(kt * 32 + q * 8 + j) * S + ncol];
      b1[j] = (short)bf_hi(w);
      b2[j] = (short)bf_hi(w - bf_hi_f(w));
    }
    B1[kt] = b1; B2[kt] = b2;
  }
  const float bcv = bcell[lane * S + ncol];
  const float wov = Wout[ncol];
  for (int idx = tid; idx < 2 * S; idx += NT)
    wg_lds[idx] = (lane > 0) ? Wcomb[(size_t)(lane - 1) * 2 * S + idx] : 0.0f;
  const float bg = (lane > 0) ? bcomb[lane - 1] : 0.0f;
  // stage/gate mapping: 32 threads per row, 16 rows; wave w owns rows 2w,2w+1
  const int grow = tid >> 5, gch = tid & 31;
  __syncthreads();   // also gates on tid0's init-flag wait

  float oacc[4] = {0.f, 0.f, 0.f, 0.f};

  for (int t = 0; t < T; ++t) {
    // ---- phase A: x stage (per-wave rows) + ALL-WAVE fused stamp poll ----
    // No barrier after: phases A and B touch only this wave's LDS rows.
    {
      const float f0 = x[(((size_t)lane * BATCH + r0 + grow) * T + t) * FIN + gch];
      A1[grow * AS + gch] = bf_hi(f0);
      A2[grow * AS + gch] = bf_hi(f0 - bf_hi_f(f0));
    }
    for (;;) {
      u32x4 so, sp, sc;
      cld3x4_glb(&so, &sp, &sc, st_own, pp_poll, pc_poll);
      bool ok = true;
      if (t > 0)                  ok &= (umin4(so) >= (unsigned)t);
      if (lane > 0)               ok &= (umin4(sp) >= (unsigned)(t + 1));
      if (lane < 3 && t >= DEPTH) ok &= (umin4(sc) >= (unsigned)(t - 3));
      if (ok) break;
      __builtin_amdgcn_s_sleep(1);
    }

    // ---- phase B: ring loads + wave-local gate (fp32) + split-stage hc ----
    {
      const int row = grow;
      float4 hv[4], pv[4];
      const float* hb = ring + ((size_t)(lane * DEPTH + ((t - 1) & 3)) * BATCH + r0 + row) * S + gch * 4;
      const float* pb = ring + ((size_t)((lane - 1) * DEPTH + (t & 3)) * BATCH + r0 + row) * S + gch * 4;
      if (t > 0) {
        if (lane > 0) cload_row2(hv, pv, hb, pb);
        else          cload_row(hv, hb);
      } else {
        #pragma unroll
        for (int j = 0; j < 4; ++j) hv[j] = make_float4(0.f, 0.f, 0.f, 0.f);
        if (lane > 0) cload_row(pv, pb);
      }
      if (lane > 0) {
        float gs = 0.0f;
        #pragma unroll
        for (int j = 0; j < 4; ++j) {
          const float* wh = &wg_lds[j * 128 + gch * 4];
          const float* wp = wh + S;
          gs += hv[j].x * wh[0] + hv[j].y * wh[1] + hv[j].z * wh[2] + hv[j].w * wh[3];
          gs += pv[j].x * wp[0] + pv[j].y * wp[1] + pv[j].z * wp[2] + pv[j].w * wp[3];
        }
        gs += __shfl_xor(gs, 1);  gs += __shfl_xor(gs, 2);  gs += __shfl_xor(gs, 4);
        gs += __shfl_xor(gs, 8);  gs += __shfl_xor(gs, 16);  // 32-lane row halves
        const float w = 1.0f / (1.0f + __expf(-(gs + bg)));
        #pragma unroll
        for (int j = 0; j < 4; ++j) {  // hc = p + w*(h-p)
          hv[j].x = fmaf(w, hv[j].x - pv[j].x, pv[j].x);
          hv[j].y = fmaf(w, hv[j].y - pv[j].y, pv[j].y);
          hv[j].z = fmaf(w, hv[j].z - pv[j].z, pv[j].z);
          hv[j].w = fmaf(w, hv[j].w - pv[j].w, pv[j].w);
        }
      }
      #pragma unroll
      for (int j = 0; j < 4; ++j) {
        ushort4 h4, l4;
        h4.x = bf_hi(hv[j].x); l4.x = bf_hi(hv[j].x - bf_hi_f(hv[j].x));
        h4.y = bf_hi(hv[j].y); l4.y = bf_hi(hv[j].y - bf_hi_f(hv[j].y));
        h4.z = bf_hi(hv[j].z); l4.z = bf_hi(hv[j].z - bf_hi_f(hv[j].z));
        h4.w = bf_hi(hv[j].w); l4.w = bf_hi(hv[j].w - bf_hi_f(hv[j].w));
        const int ai = row * AS + 32 + j * 128 + gch * 4;
        *(ushort4*)&A1[ai] = h4;
        *(ushort4*)&A2[ai] = l4;
      }
    }
    __syncthreads();

    // ---- phase C: MFMA 16x16 tile, 17 K-tiles x 3 split products ----------
    f32x4 acc = {0.f, 0.f, 0.f, 0.f};
    {
      const unsigned short* ar1 = &A1[bn * AS + q * 8];
      const unsigned short* ar2 = &A2[bn * AS + q * 8];
      #pragma unroll
      for (int kt = 0; kt < NKT; ++kt) {
        const short8 a1 = *(const short8*)(ar1 + kt * 32);
        const short8 a2 = *(const short8*)(ar2 + kt * 32);
        acc = __builtin_amdgcn_mfma_f32_16x16x32_bf16(a1, B1[kt], acc, 0, 0, 0);
        acc = __builtin_amdgcn_mfma_f32_16x16x32_bf16(a1, B2[kt], acc, 0, 0, 0);
        acc = __builtin_amdgcn_mfma_f32_16x16x32_bf16(a2, B1[kt], acc, 0, 0, 0);
      }
    }

    // ---- epilogue: +bias, tanh, coherent ring store (D-layout direct) -----
    float* slot = ring + ((size_t)(lane * DEPTH + (t & 3)) * BATCH + r0) * S + sb;
    #pragma unroll
    for (int reg = 0; reg < 4; ++reg) {
      const float s2 = acc[reg] + bcv;
      const float aa = fabsf(s2), ee = __expf(2.0f * aa);
      const float tv = copysignf(1.0f - 2.0f / (ee + 1.0f), s2);
      cstore1(slot + (size_t)(q * 4 + reg) * S + wt * 16 + bn, tv);
      if (t == T - 1) oacc[reg] = tv * wov;
    }
    asm volatile("s_waitcnt vmcnt(0)" ::: "memory");  // own stores at MALL
    __syncthreads();  // all threads drained -> safe to stamp + reuse A-LDS
    if (tid == 0) cstoreu_glb(st_mine, (unsigned)(t + 1));
  }

  // ---- output: out[lane*256 + r] = h_T[r] . Wout --------------------------
  #pragma unroll
  for (int reg = 0; reg < 4; ++reg) {
    float v = oacc[reg];
    v += __shfl_xor(v, 1); v += __shfl_xor(v, 2);
    v += __shfl_xor(v, 4); v += __shfl_xor(v, 8);  // sum 16 cols of the tile
    if (bn == 0) obuf[wt * 16 + q * 4 + reg] = v;
  }
  __syncthreads();
  if (tid < 16) {
    float v = 0.0f;
    #pragma unroll
    for (int w = 0; w < 8; ++w) v += obuf[w * 16 + tid];
    cstore1(ws + OUTP_OFF + (size_t)((gid * 4 + sl) * 16 + tid), v);
  }
  asm volatile("s_waitcnt vmcnt(0)" ::: "memory");
  __syncthreads();
  if (tid == 0) cstoreu_glb(st_mine, (unsigned)(T + 1));
  if (sl == 0) {
    if (tid == 0)
      while (umin4(cld4_glb(st_own)) < (unsigned)(T + 1)) __builtin_amdgcn_s_sleep(1);
    __syncthreads();
    if (tid < 64) {
      const int sli = tid >> 4, r = tid & 15;
      fbuf[tid] = cload1(ws + OUTP_OFF + (size_t)((gid * 4 + sli) * 16 + r));
    }
    __syncthreads();
    if (tid < 16) {
      float s2 = 0.f;
      #pragma unroll
      for (int sli = 0; sli < 4; ++sli) s2 += fbuf[sli * 16 + tid];
      out[lane * BATCH + r0 + tid] = s2;
    }
  }
}

extern "C" void kernel_launch(void* const* d_in, const int* in_sizes, int n_in,
                              void* d_out, int out_size, void* d_ws, size_t ws_size,
                              hipStream_t stream) {
  (void)in_sizes; (void)n_in; (void)out_size; (void)ws_size;
  rnn_mfma<<<dim3(NWG), dim3(NT), 0, stream>>>(
      (const float*)d_in[0],   // inputs
      (const float*)d_in[1],   // W_cell
      (const float*)d_in[2],   // b_cell
      (const float*)d_in[3],   // W_comb
      (const float*)d_in[4],   // b_comb
      (const float*)d_in[5],   // W_out
      (float*)d_out,
      (float*)d_ws);
}